// Round 3
// baseline (166.619 us; speedup 1.0000x reference)
//
#include <hip/hip_runtime.h>
#include <hip/hip_bf16.h>
#include <math.h>

#define B_    32
#define L_    4096
#define D_    512
#define NST   64
#define UNITS 512
#define ROWS  (B_ * L_)          // 131072
#define PI_F  3.14159265358979323846f
#define ROWU  20                 // uints per 32-k LDS row (80 B: bank spread, 2-way max)
#define HLOG2E 0.7213475204444817f   // 0.5*log2(e)
#define TLOG2E 2.8853900817779268f   // 2*log2(e)

typedef __attribute__((ext_vector_type(8))) short short8;
typedef __attribute__((ext_vector_type(4))) float f32x4;

__device__ inline float fexp2(float x) { return __builtin_amdgcn_exp2f(x); }
__device__ inline float frcp(float x)  { return __builtin_amdgcn_rcpf(x); }
__device__ inline float fsin1(float r) { return __builtin_amdgcn_sinf(r); }  // sin(2*pi*r)
__device__ inline float fcos1(float r) { return __builtin_amdgcn_cosf(r); }  // cos(2*pi*r)
__device__ inline float ftanh(float y) {
    float e = fexp2(y * TLOG2E);               // e^(2y)
    return 1.0f - 2.0f * frcp(e + 1.0f);
}

__device__ inline ushort f2bf(float f) {
    uint u = __float_as_uint(f);
    return (ushort)((u + 0x7fffu + ((u >> 16) & 1u)) >> 16);   // RNE
}
__device__ inline float bf2f(ushort h) { return __uint_as_float(((uint)h) << 16); }

// split two f32 into packed bf16 hi + packed bf16 lo (RNE both, via v_cvt_pk)
__device__ inline void split2(float f0, float f1, uint& hi, uint& lo) {
    __hip_bfloat162 h2 = __float22bfloat162_rn(make_float2(f0, f1));
    hi = *reinterpret_cast<uint*>(&h2);
    float h0 = __uint_as_float(hi << 16);
    float h1 = __uint_as_float(hi & 0xffff0000u);
    __hip_bfloat162 l2 = __float22bfloat162_rn(make_float2(f0 - h0, f1 - h1));
    lo = *reinterpret_cast<uint*>(&l2);
}

__device__ inline void onl(float& m, float& s, float m2, float s2) {
    float nm = fmaxf(m, m2);
    s = s * fexp2((m - nm) * 1.4426950408889634f) + s2 * fexp2((m2 - nm) * 1.4426950408889634f);
    m = nm;
}

// ---------------- workspace layout (bytes) ----------------
#define OFF_WHT   ((size_t)0)                                   // [128][512] bf16 hi (W^T, permuted cols)
#define OFF_WLT   (OFF_WHT   + (size_t)128 * 512 * 2)           // [128][512] bf16 lo
#define OFF_PSW   (OFF_WLT   + (size_t)128 * 512 * 2)           // [512][2] f32 psi weights
#define OFF_UV    (OFF_PSW   + (size_t)512 * 2 * 4)             // [ROWS][64][2] f32 (u,v) unnormalized
#define OFF_ZPSI  (OFF_UV    + (size_t)ROWS * 128 * 4)          // [ROWS][2] f32
#define OFF_PMPHI (OFF_ZPSI  + (size_t)ROWS * 2 * 4)            // [1024][64]
#define OFF_PSPHI (OFF_PMPHI + (size_t)1024 * 64 * 4)
#define OFF_PMPSI (OFF_PSPHI + (size_t)1024 * 64 * 4)           // [1024]
#define OFF_PSPSI (OFF_PMPSI + (size_t)1024 * 4)
#define OFF_SPHI  (OFF_PSPSI + (size_t)1024 * 4)                // [32][64] combined scale
#define OFF_SPSI  (OFF_SPHI  + (size_t)32 * 64 * 4)             // [32]
#define OFF_PRI   OFF_PMPHI   // [32][16][128] aliases pmphi/psphi (dead after k2_final)

// K0: split weights into bf16 hi/lo, W^T layout with column permutation:
// packed col for r_n is p=( (n>>5)<<6 )|(n&31), for t_n is p+32 -> each wave
// (64 packed cols) holds 32 r-cols and their matching 32 t-cols.
__global__ void k0_pack(const float* __restrict__ psi_r, const float* __restrict__ psi_t,
                        const float* __restrict__ phi_r, const float* __restrict__ phi_t,
                        ushort* __restrict__ wht, ushort* __restrict__ wlt,
                        float* __restrict__ psw) {
    const int k = blockIdx.x;     // 0..511
    const int n = threadIdx.x;    // 0..63
    const int pr = ((n >> 5) << 6) | (n & 31);
    const int pt = pr + 32;
    float w0 = phi_r[k * 64 + n];
    float w1 = phi_t[k * 64 + n];
    ushort h0 = f2bf(w0), h1 = f2bf(w1);
    wht[(size_t)pr * 512 + k] = h0;
    wht[(size_t)pt * 512 + k] = h1;
    wlt[(size_t)pr * 512 + k] = f2bf(w0 - bf2f(h0));
    wlt[(size_t)pt * 512 + k] = f2bf(w1 - bf2f(h1));
    if (n == 0) { psw[k * 2 + 0] = psi_r[k]; psw[k * 2 + 1] = psi_t[k]; }
}

// K1: z = x @ W via 3-pass split-bf16 MFMA; epilogue transforms z -> (u,v) =
// exp(z_r/2)*(cos phi, sin phi) with HW transcendentals, so downstream is pure FMA.
// Fused per-block softmax partials (phi r-cols + psi). x/W reg-prefetch per k-step.
__global__ __launch_bounds__(256, 3) void k1_gemm(
        const float* __restrict__ x, const uint* __restrict__ wht, const uint* __restrict__ wlt,
        const float* __restrict__ psw_g, const float* __restrict__ phi_tb_p,
        float* __restrict__ uv, float* __restrict__ zpsi,
        float* __restrict__ pmphi, float* __restrict__ psphi,
        float* __restrict__ pmpsi, float* __restrict__ pspsi) {
    __shared__ uint Ah[128 * ROWU], Al[128 * ROWU];
    __shared__ uint Bh[128 * ROWU], Bl[128 * ROWU];
    __shared__ __align__(16) float2 pswl[512];
    __shared__ float stat_m[4][32], stat_s[4][32];
    __shared__ float psr[128];

    const int t    = threadIdx.x;
    const int lane = t & 63;
    const int w = t >> 6, wr = w >> 1, wc = w & 1;
    const int r0 = blockIdx.x * 128;
    const int hi16 = lane >> 4, lo16 = lane & 15;

    ((float4*)pswl)[t] = ((const float4*)psw_g)[t];

    f32x4 acc[4][4];
    #pragma unroll
    for (int i = 0; i < 4; ++i)
        #pragma unroll
        for (int j = 0; j < 4; ++j) acc[i][j] = (f32x4)0.f;

    float paccr[4] = {0.f, 0.f, 0.f, 0.f}, pacct[4] = {0.f, 0.f, 0.f, 0.f};
    const int xrow = t >> 3, xj = t & 7;   // x stage: rows (t>>3)+32p, float4 idx xj
    const int wn = t >> 2, jw = t & 3;     // W stage: rows (t>>2)+64p, uint4 idx jw

    // prologue: load k-tile 0 into regs
    float4 xv[4];
    uint4 bvh[2], bvl[2];
    #pragma unroll
    for (int p = 0; p < 4; ++p)
        xv[p] = *(const float4*)&x[(size_t)(r0 + xrow + 32 * p) * 512 + xj * 4];
    #pragma unroll
    for (int p = 0; p < 2; ++p) {
        const size_t gi = (size_t)(wn + 64 * p) * 256 + jw * 4;
        bvh[p] = *(const uint4*)&wht[gi];
        bvl[p] = *(const uint4*)&wlt[gi];
    }
    __syncthreads();   // pswl ready

    #pragma unroll 1
    for (int kt = 0; kt < 512; kt += 32) {
        // psi partial dots (fp32)
        #pragma unroll
        for (int e = 0; e < 4; ++e) {
            float2 ww = pswl[kt + xj * 4 + e];
            #pragma unroll
            for (int p = 0; p < 4; ++p) {
                float xe = ((const float*)&xv[p])[e];
                paccr[p] = fmaf(xe, ww.x, paccr[p]);
                pacct[p] = fmaf(xe, ww.y, pacct[p]);
            }
        }
        // split + stage A
        #pragma unroll
        for (int p = 0; p < 4; ++p) {
            const float* xe = (const float*)&xv[p];
            uint h0, l0, h1, l1;
            split2(xe[0], xe[1], h0, l0);
            split2(xe[2], xe[3], h1, l1);
            const int off = (xrow + 32 * p) * ROWU + xj * 2;
            *(uint2*)&Ah[off] = make_uint2(h0, h1);
            *(uint2*)&Al[off] = make_uint2(l0, l1);
        }
        // stage B
        #pragma unroll
        for (int p = 0; p < 2; ++p) {
            const int n = wn + 64 * p;
            *(uint4*)&Bh[n * ROWU + jw * 4] = bvh[p];
            *(uint4*)&Bl[n * ROWU + jw * 4] = bvl[p];
        }
        __syncthreads();

        // prefetch next k-tile into regs (hides HBM latency under MFMA phase)
        if (kt < 480) {
            #pragma unroll
            for (int p = 0; p < 4; ++p)
                xv[p] = *(const float4*)&x[(size_t)(r0 + xrow + 32 * p) * 512 + kt + 32 + xj * 4];
            #pragma unroll
            for (int p = 0; p < 2; ++p) {
                const size_t gi = (size_t)(wn + 64 * p) * 256 + ((kt + 32) >> 1) + jw * 4;
                bvh[p] = *(const uint4*)&wht[gi];
                bvl[p] = *(const uint4*)&wlt[gi];
            }
        }

        short8 ahf[4], alf[4];
        #pragma unroll
        for (int mi = 0; mi < 4; ++mi) {
            const int off = (wr * 64 + mi * 16 + lo16) * ROWU + hi16 * 4;
            ahf[mi] = *(const short8*)&Ah[off];
            alf[mi] = *(const short8*)&Al[off];
        }
        #pragma unroll
        for (int nj = 0; nj < 4; ++nj) {
            const int off = (wc * 64 + nj * 16 + lo16) * ROWU + hi16 * 4;
            short8 bhf = *(const short8*)&Bh[off];
            short8 blf = *(const short8*)&Bl[off];
            #pragma unroll
            for (int mi = 0; mi < 4; ++mi) {
                acc[mi][nj] = __builtin_amdgcn_mfma_f32_16x16x32_bf16(ahf[mi], bhf, acc[mi][nj], 0, 0, 0);
                acc[mi][nj] = __builtin_amdgcn_mfma_f32_16x16x32_bf16(ahf[mi], blf, acc[mi][nj], 0, 0, 0);
                acc[mi][nj] = __builtin_amdgcn_mfma_f32_16x16x32_bf16(alf[mi], bhf, acc[mi][nj], 0, 0, 0);
            }
        }
        __syncthreads();
    }

    // ---- epilogue: z -> (u,v) with HW trans; fused softmax partials ----
    const float phi_tb = phi_tb_p[0];
    #pragma unroll
    for (int nj = 0; nj < 2; ++nj) {
        const int n = wc * 32 + nj * 16 + lo16;       // true state index 0..63
        float m = -3.4e38f, s = 0.f;
        #pragma unroll
        for (int mi = 0; mi < 4; ++mi) {
            const int rowg = r0 + wr * 64 + mi * 16 + hi16 * 4;
            #pragma unroll
            for (int r = 0; r < 4; ++r) {
                float zr = acc[mi][nj][r];            // phi_r column n
                float zt = acc[mi][nj + 2][r];        // matching phi_theta column n
                float eh = fexp2(zr * HLOG2E);        // exp(zr/2), unnormalized
                float tt = ftanh(zt + phi_tb);
                float rev = -(1.0f + PI_F * tt) * 0.5f;   // phi angle in revolutions
                float rf = rev - floorf(rev);
                float cB = fcos1(rf), sB = fsin1(rf);
                *(float2*)&uv[(size_t)(rowg + r) * 128 + n * 2] = make_float2(eh * cB, eh * sB);
                float nm = fmaxf(m, zr);
                s = s * fexp2((m - nm) * 1.4426950408889634f) + fexp2((zr - nm) * 1.4426950408889634f);
                m = nm;
            }
        }
        // combine across hi16 groups (rows) -> per-column stats
        #pragma unroll
        for (int off = 16; off <= 32; off <<= 1) {
            float m2 = __shfl_xor(m, off);
            float s2 = __shfl_xor(s, off);
            onl(m, s, m2, s2);
        }
        if (lane < 16) { stat_m[w][nj * 16 + lo16] = m; stat_s[w][nj * 16 + lo16] = s; }
    }
    // psi: reduce the 8 k-segment partials per row
    #pragma unroll
    for (int p = 0; p < 4; ++p) {
        #pragma unroll
        for (int off = 1; off <= 4; off <<= 1) {
            paccr[p] += __shfl_xor(paccr[p], off);
            pacct[p] += __shfl_xor(pacct[p], off);
        }
    }
    if (xj == 0) {
        #pragma unroll
        for (int p = 0; p < 4; ++p) {
            const int row = xrow + 32 * p;
            ((float2*)zpsi)[r0 + row] = make_float2(paccr[p], pacct[p]);
            psr[row] = paccr[p];
        }
    }
    __syncthreads();
    if (t < 64) {
        const int wcn = t >> 5, nloc = t & 31;
        float M = stat_m[wcn][nloc], S = stat_s[wcn][nloc];
        onl(M, S, stat_m[wcn + 2][nloc], stat_s[wcn + 2][nloc]);
        pmphi[(size_t)blockIdx.x * 64 + t] = M;
        psphi[(size_t)blockIdx.x * 64 + t] = S;
    } else if (t < 128) {
        const int i = t - 64;
        float a = psr[i], bb = psr[i + 64];
        float M = fmaxf(a, bb);
        float S = fexp2((a - M) * 1.4426950408889634f) + fexp2((bb - M) * 1.4426950408889634f);
        #pragma unroll
        for (int off = 1; off <= 32; off <<= 1) {
            float m2 = __shfl_xor(M, off);
            float s2 = __shfl_xor(S, off);
            onl(M, S, m2, s2);
        }
        if (i == 0) { pmpsi[blockIdx.x] = M; pspsi[blockIdx.x] = S; }
    }
}

// K2: combine 1024 per-block partials -> combined scale exp(-m/2)/sqrt(S)
__global__ void k2_final(const float* __restrict__ pmphi, const float* __restrict__ psphi,
                         const float* __restrict__ pmpsi, const float* __restrict__ pspsi,
                         float* __restrict__ sphi, float* __restrict__ spsi) {
    const int b = blockIdx.x, t = threadIdx.x;
    if (t < 64) {
        float M = -3.4e38f, S = 0.f;
        for (int ch = 0; ch < 32; ++ch)
            onl(M, S, pmphi[(size_t)(b * 32 + ch) * 64 + t], psphi[(size_t)(b * 32 + ch) * 64 + t]);
        sphi[b * 64 + t] = fexp2(-M * HLOG2E) / sqrtf(S);
    } else if (t == 64) {
        float M = -3.4e38f, S = 0.f;
        for (int ch = 0; ch < 32; ++ch)
            onl(M, S, pmpsi[b * 32 + ch], pspsi[b * 32 + ch]);
        spsi[b] = fexp2(-M * HLOG2E) / sqrtf(S);
    }
}

// K4: pure-FMA weighted reduction over L (memory-bound). psi amplitude-phase
// per row computed once into LDS with HW trans; 256 rows per block.
__global__ __launch_bounds__(256) void k4_reduce(
        const float* __restrict__ uv, const float* __restrict__ zpsi,
        const float* __restrict__ psi_tb_p, float* __restrict__ pri) {
    const int b = blockIdx.x, ch = blockIdx.y, t = threadIdx.x;
    const int base = b * L_ + ch * 256;
    __shared__ float als[256], bls[256];
    __shared__ float red[16][128];

    {
        const float psi_tb = psi_tb_p[0];
        float2 zp = ((const float2*)zpsi)[base + t];
        float e = fexp2(zp.x * HLOG2E);               // unnormalized psi amplitude
        float tt = ftanh(zp.y + psi_tb);
        float rev = (1.0f + tt) * 0.5f;               // psi angle in revolutions, in (0,1)
        als[t] = e * fcos1(rev);
        bls[t] = e * fsin1(rev);
    }
    __syncthreads();

    const int c8 = t & 15, q = t >> 4;
    float re[4] = {0.f, 0.f, 0.f, 0.f}, im[4] = {0.f, 0.f, 0.f, 0.f};
    for (int li = q; li < 256; li += 16) {
        const float* row = &uv[(size_t)(base + li) * 128 + c8 * 8];
        float4 v0 = ((const float4*)row)[0];
        float4 v1 = ((const float4*)row)[1];
        float a = als[li], bb = bls[li];
        re[0] += a * v0.x + bb * v0.y;  im[0] += bb * v0.x - a * v0.y;
        re[1] += a * v0.z + bb * v0.w;  im[1] += bb * v0.z - a * v0.w;
        re[2] += a * v1.x + bb * v1.y;  im[2] += bb * v1.x - a * v1.y;
        re[3] += a * v1.z + bb * v1.w;  im[3] += bb * v1.z - a * v1.w;
    }
    #pragma unroll
    for (int j = 0; j < 4; ++j) {
        red[q][c8 * 8 + 2 * j]     = re[j];
        red[q][c8 * 8 + 2 * j + 1] = im[j];
    }
    __syncthreads();
    if (t < 128) {
        float sum = 0.f;
        #pragma unroll
        for (int qq = 0; qq < 16; ++qq) sum += red[qq][t];
        pri[((size_t)(b * 16 + ch)) * 128 + t] = sum;
    }
}

// K5: combine chunk partials, apply normalization scales, collapse, output GEMM
__global__ __launch_bounds__(512) void k5_out(const float* __restrict__ pri,
                                              const float* __restrict__ sphi,
                                              const float* __restrict__ spsi,
                                              const float* __restrict__ Smat,
                                              const float* __restrict__ sb_p,
                                              float* __restrict__ out) {
    const int b = blockIdx.x, t = threadIdx.x;
    __shared__ float cls[64];
    if (t < 64) {
        float re = 0.f, im = 0.f;
        for (int ch = 0; ch < 16; ++ch) {
            re += pri[((size_t)(b * 16 + ch)) * 128 + t * 2 + 0];
            im += pri[((size_t)(b * 16 + ch)) * 128 + t * 2 + 1];
        }
        float sc = spsi[b] * sphi[b * 64 + t];
        cls[t] = sc * sc * (re * re + im * im);
    }
    __syncthreads();
    float acc = sb_p[0];
    #pragma unroll 8
    for (int n = 0; n < 64; ++n) acc = fmaf(cls[n], Smat[n * UNITS + t], acc);
    out[(size_t)b * UNITS + t] = acc;
}

extern "C" void kernel_launch(void* const* d_in, const int* in_sizes, int n_in,
                              void* d_out, int out_size, void* d_ws, size_t ws_size,
                              hipStream_t stream) {
    const float* x      = (const float*)d_in[0];
    const float* psi_r  = (const float*)d_in[1];
    const float* psi_t  = (const float*)d_in[2];
    const float* psi_tb = (const float*)d_in[3];
    const float* phi_r  = (const float*)d_in[4];
    const float* phi_t  = (const float*)d_in[5];
    const float* phi_tb = (const float*)d_in[6];
    const float* Smat   = (const float*)d_in[7];
    const float* sb     = (const float*)d_in[8];
    float* out = (float*)d_out;

    char* ws = (char*)d_ws;
    ushort* wht  = (ushort*)(ws + OFF_WHT);
    ushort* wlt  = (ushort*)(ws + OFF_WLT);
    float* psw   = (float*)(ws + OFF_PSW);
    float* uv    = (float*)(ws + OFF_UV);
    float* zpsi  = (float*)(ws + OFF_ZPSI);
    float* pmphi = (float*)(ws + OFF_PMPHI);
    float* psphi = (float*)(ws + OFF_PSPHI);
    float* pmpsi = (float*)(ws + OFF_PMPSI);
    float* pspsi = (float*)(ws + OFF_PSPSI);
    float* sphi  = (float*)(ws + OFF_SPHI);
    float* spsi  = (float*)(ws + OFF_SPSI);
    float* pri   = (float*)(ws + OFF_PRI);

    k0_pack<<<512, 64, 0, stream>>>(psi_r, psi_t, phi_r, phi_t, wht, wlt, psw);
    k1_gemm<<<ROWS / 128, 256, 0, stream>>>(x, (const uint*)wht, (const uint*)wlt, psw, phi_tb,
                                            uv, zpsi, pmphi, psphi, pmpsi, pspsi);
    k2_final<<<B_, 128, 0, stream>>>(pmphi, psphi, pmpsi, pspsi, sphi, spsi);
    k4_reduce<<<dim3(B_, 16), 256, 0, stream>>>(uv, zpsi, psi_tb, pri);
    k5_out<<<B_, 512, 0, stream>>>(pri, sphi, spsi, Smat, sb, out);
}

// Round 5
// 93.557 us; speedup vs baseline: 1.7809x; 1.7809x over previous
//
#include <hip/hip_runtime.h>
#include <hip/hip_bf16.h>
#include <math.h>

#define B_    32
#define L_    4096
#define UNITS 512
#define ROWS  (B_ * L_)          // 131072
#define PI_F  3.14159265358979323846f
#define ROWU  20                 // uints per 32-k LDS row (80 B pad: <=2-way bank alias)
#define HLOG2E 0.7213475204444817f   // 0.5*log2(e)
#define LOG2E  1.4426950408889634f
#define TLOG2E 2.8853900817779268f   // 2*log2(e)

typedef __attribute__((ext_vector_type(8))) short short8;
typedef __attribute__((ext_vector_type(4))) float f32x4;

__device__ inline float fexp2(float x) { return __builtin_amdgcn_exp2f(x); }
__device__ inline float frcp(float x)  { return __builtin_amdgcn_rcpf(x); }
__device__ inline float fsin1(float r) { return __builtin_amdgcn_sinf(r); }  // sin(2*pi*r)
__device__ inline float fcos1(float r) { return __builtin_amdgcn_cosf(r); }  // cos(2*pi*r)
__device__ inline float ftanh(float y) {
    float e = fexp2(y * TLOG2E);               // e^(2y)
    return 1.0f - 2.0f * frcp(e + 1.0f);
}

__device__ inline ushort f2bf(float f) {
    uint u = __float_as_uint(f);
    return (ushort)((u + 0x7fffu + ((u >> 16) & 1u)) >> 16);   // RNE
}
__device__ inline float bf2f(ushort h) { return __uint_as_float(((uint)h) << 16); }

// split two f32 into packed bf16 hi + packed bf16 lo (RNE both)
__device__ inline void split2(float f0, float f1, uint& hi, uint& lo) {
    __hip_bfloat162 h2 = __float22bfloat162_rn(make_float2(f0, f1));
    hi = *reinterpret_cast<uint*>(&h2);
    float h0 = __uint_as_float(hi << 16);
    float h1 = __uint_as_float(hi & 0xffff0000u);
    __hip_bfloat162 l2 = __float22bfloat162_rn(make_float2(f0 - h0, f1 - h1));
    lo = *reinterpret_cast<uint*>(&l2);
}

__device__ inline void onl(float& m, float& s, float m2, float s2) {
    float nm = fmaxf(m, m2);
    s = s * fexp2((m - nm) * LOG2E) + s2 * fexp2((m2 - nm) * LOG2E);
    m = nm;
}

// ---------------- workspace layout (bytes), total ~1.3 MB ----------------
#define OFF_WHT   ((size_t)0)                    // [128][512] bf16 hi (W^T, permuted cols)
#define OFF_WLT   (OFF_WHT + (size_t)131072)     // [128][512] bf16 lo
#define OFF_PSW   (OFF_WLT + (size_t)131072)     // [512] float2 psi weights
#define OFF_PRI   (OFF_PSW + (size_t)4096)       // [1024][64] float2 partial re/im
#define OFF_PMPHI (OFF_PRI + (size_t)524288)     // [1024][64] f32
#define OFF_PSPHI (OFF_PMPHI + (size_t)262144)
#define OFF_PMPSI (OFF_PSPHI + (size_t)262144)   // [1024]
#define OFF_PSPSI (OFF_PMPSI + (size_t)4096)

// K0 (verbatim R3, battle-tested): split weights into bf16 hi/lo, W^T [128][512]
// with column permutation: packed col for phi_r col n is pr=((n>>5)<<6)|(n&31),
// for phi_theta col n it is pr+32 -> each wave's 64 packed cols = 32 r-cols +
// their matching 32 t-cols.
__global__ void k0_pack(const float* __restrict__ psi_r, const float* __restrict__ psi_t,
                        const float* __restrict__ phi_r, const float* __restrict__ phi_t,
                        ushort* __restrict__ wht, ushort* __restrict__ wlt,
                        float2* __restrict__ psw) {
    const int k = blockIdx.x;     // 0..511
    const int n = threadIdx.x;    // 0..63
    const int pr = ((n >> 5) << 6) | (n & 31);
    const int pt = pr + 32;
    float w0 = phi_r[k * 64 + n];
    float w1 = phi_t[k * 64 + n];
    ushort h0 = f2bf(w0), h1 = f2bf(w1);
    wht[(size_t)pr * 512 + k] = h0;
    wht[(size_t)pt * 512 + k] = h1;
    wlt[(size_t)pr * 512 + k] = f2bf(w0 - bf2f(h0));
    wlt[(size_t)pt * 512 + k] = f2bf(w1 - bf2f(h1));
    if (n == 0) psw[k] = make_float2(psi_r[k], psi_t[k]);
}

// K1: z = x @ W via 3-pass split-bf16 MFMA (A and B LDS-staged, R2/R3-verified
// main loop). Fused epilogue: psi amplitude-phase per row; phi (u,v) staged
// through an LDS tile (reusing dead A/B staging LDS) and reduced with explicit
// (row,state) indexing -> partial re/im per block; softmax partials fused.
__global__ __launch_bounds__(256) void k1_gemm(
        const float* __restrict__ x,
        const uint* __restrict__ wht, const uint* __restrict__ wlt,
        const float2* __restrict__ psw_g,
        const float* __restrict__ psi_tb_p, const float* __restrict__ phi_tb_p,
        float2* __restrict__ pri,
        float* __restrict__ pmphi, float* __restrict__ psphi,
        float* __restrict__ pmpsi, float* __restrict__ pspsi) {
    __shared__ __align__(16) uint smem4[4 * 2560];      // Ah|Al|Bh|Bl, 40960 B
    uint* const Ah = smem4;
    uint* const Al = smem4 + 2560;
    uint* const Bh = smem4 + 5120;
    uint* const Bl = smem4 + 7680;
    float2* const zuv = (float2*)smem4;                 // epilogue alias: [128][33] pairs (33792 B)
    __shared__ __align__(16) float2 pswl[512];          // 4096 B
    __shared__ float als[128], bls[128], psr[128];
    __shared__ float stat_m[4][32], stat_s[4][32];
    __shared__ float2 red[8][32];

    const int t    = threadIdx.x;
    const int lane = t & 63;
    const int w = t >> 6, wr = w >> 1, wc = w & 1;
    const int r0 = blockIdx.x * 128;
    const int hi16 = lane >> 4, lo16 = lane & 15;

    ((float4*)pswl)[t] = ((const float4*)psw_g)[t];     // 4 KB

    f32x4 acc[4][4];
    #pragma unroll
    for (int i = 0; i < 4; ++i)
        #pragma unroll
        for (int j = 0; j < 4; ++j) acc[i][j] = (f32x4)0.f;

    float paccr[4] = {0.f, 0.f, 0.f, 0.f}, pacct[4] = {0.f, 0.f, 0.f, 0.f};
    const int xrow = t >> 3, xj = t & 7;   // x stage: rows (t>>3)+32p, float4 idx xj
    const int wn = t >> 2, jw = t & 3;     // W stage: rows (t>>2)+64p, uint4 idx jw

    for (int kt = 0; kt < 512; kt += 32) {
        __syncthreads();    // prev iter's fragment reads done (also covers pswl on iter 0)
        // ---- stage A (x -> bf16 hi/lo in LDS) + psi partial dots ----
        float4 xv[4];
        #pragma unroll
        for (int p = 0; p < 4; ++p)
            xv[p] = *(const float4*)&x[(size_t)(r0 + xrow + 32 * p) * 512 + kt + xj * 4];
        #pragma unroll
        for (int e = 0; e < 4; ++e) {
            float2 ww = pswl[kt + xj * 4 + e];
            #pragma unroll
            for (int p = 0; p < 4; ++p) {
                float xe = ((const float*)&xv[p])[e];
                paccr[p] = fmaf(xe, ww.x, paccr[p]);
                pacct[p] = fmaf(xe, ww.y, pacct[p]);
            }
        }
        #pragma unroll
        for (int p = 0; p < 4; ++p) {
            const float* xe = (const float*)&xv[p];
            uint h0, l0, h1, l1;
            split2(xe[0], xe[1], h0, l0);
            split2(xe[2], xe[3], h1, l1);
            const int off = (xrow + 32 * p) * ROWU + xj * 2;
            *(uint2*)&Ah[off] = make_uint2(h0, h1);
            *(uint2*)&Al[off] = make_uint2(l0, l1);
        }
        // ---- stage B (row-major W^T from ws, R2/R3-verified) ----
        #pragma unroll
        for (int p = 0; p < 2; ++p) {
            const int n = wn + 64 * p;
            const size_t gi = (size_t)n * 256 + (kt >> 1) + jw * 4;
            uint4 vh = *(const uint4*)&wht[gi];
            uint4 vl = *(const uint4*)&wlt[gi];
            *(uint4*)&Bh[n * ROWU + jw * 4] = vh;
            *(uint4*)&Bl[n * ROWU + jw * 4] = vl;
        }
        __syncthreads();

        // ---- MFMA phase (R2/R3-verified fragment reads) ----
        short8 ahf[4], alf[4];
        #pragma unroll
        for (int mi = 0; mi < 4; ++mi) {
            const int off = (wr * 64 + mi * 16 + lo16) * ROWU + hi16 * 4;
            ahf[mi] = *(const short8*)&Ah[off];
            alf[mi] = *(const short8*)&Al[off];
        }
        #pragma unroll
        for (int nj = 0; nj < 4; ++nj) {
            const int off = (wc * 64 + nj * 16 + lo16) * ROWU + hi16 * 4;
            short8 bhf = *(const short8*)&Bh[off];
            short8 blf = *(const short8*)&Bl[off];
            #pragma unroll
            for (int mi = 0; mi < 4; ++mi) {
                acc[mi][nj] = __builtin_amdgcn_mfma_f32_16x16x32_bf16(ahf[mi], bhf, acc[mi][nj], 0, 0, 0);
                acc[mi][nj] = __builtin_amdgcn_mfma_f32_16x16x32_bf16(ahf[mi], blf, acc[mi][nj], 0, 0, 0);
                acc[mi][nj] = __builtin_amdgcn_mfma_f32_16x16x32_bf16(alf[mi], bhf, acc[mi][nj], 0, 0, 0);
            }
        }
    }

    // ================= epilogue =================
    // part 1: psi — reduce 8 k-segment partials per row; amplitude-phase -> LDS
    #pragma unroll
    for (int p = 0; p < 4; ++p) {
        #pragma unroll
        for (int off = 1; off <= 4; off <<= 1) {
            paccr[p] += __shfl_xor(paccr[p], off);
            pacct[p] += __shfl_xor(pacct[p], off);
        }
    }
    if (xj == 0) {
        const float psi_tb = psi_tb_p[0];
        #pragma unroll
        for (int p = 0; p < 4; ++p) {
            const int row = xrow + 32 * p;
            float zr = paccr[p], zt = pacct[p];
            float e = fexp2(zr * HLOG2E);                 // unnormalized amplitude
            float tt = ftanh(zt + psi_tb);
            float rev = (1.0f + tt) * 0.5f;               // psi angle in revolutions
            als[row] = e * fcos1(rev);
            bls[row] = e * fsin1(rev);
            psr[row] = zr;
        }
    }
    __syncthreads();   // MFMA reads of smem4 done -> safe to alias as zuv; als/bls/psr visible

    // part 2: two passes over nj; each pass stages (u,v) for 32 states in LDS,
    // then reduces over rows with explicit (row, state) indexing.
    const float phi_tb = phi_tb_p[0];
    #pragma unroll
    for (int nj = 0; nj < 2; ++nj) {
        // (a) compute u,v; write to zuv; online softmax stats on z_r
        float m = -3.4e38f, s = 0.f;
        #pragma unroll
        for (int mi = 0; mi < 4; ++mi) {
            #pragma unroll
            for (int r = 0; r < 4; ++r) {
                float zr = acc[mi][nj][r];                // phi_r col (wc*32 + nj*16 + lo16)
                float zt = acc[mi][nj + 2][r];            // matching phi_theta col
                float eh = fexp2(zr * HLOG2E);
                float tt = ftanh(zt + phi_tb);
                float rev = -(1.0f + PI_F * tt) * 0.5f;
                rev = rev - floorf(rev);
                float u = eh * fcos1(rev), v = eh * fsin1(rev);
                const int row = wr * 64 + mi * 16 + hi16 * 4 + r;
                zuv[row * 33 + wc * 16 + lo16] = make_float2(u, v);
                float nm = fmaxf(m, zr);
                s = s * fexp2((m - nm) * LOG2E) + fexp2((zr - nm) * LOG2E);
                m = nm;
            }
        }
        #pragma unroll
        for (int off = 16; off <= 32; off <<= 1) {
            float m2 = __shfl_xor(m, off);
            float s2 = __shfl_xor(s, off);
            onl(m, s, m2, s2);
        }
        if (lane < 16) { stat_m[w][nj * 16 + lo16] = m; stat_s[w][nj * 16 + lo16] = s; }
        __syncthreads();

        // (b) layout-free reduction: slot = wc*16+lo16 column of zuv
        {
            const int slot = t & 31, q = t >> 5;
            float re = 0.f, im = 0.f;
            #pragma unroll
            for (int i = 0; i < 16; ++i) {
                const int row = q + 8 * i;
                float2 uvv = zuv[row * 33 + slot];
                float a = als[row], b2 = bls[row];
                re = fmaf(a, uvv.x, fmaf(b2, uvv.y, re));   // cos(A-B) identity
                im = fmaf(b2, uvv.x, fmaf(-a, uvv.y, im));  // sin(A-B) identity
            }
            red[q][slot] = make_float2(re, im);
        }
        __syncthreads();
        if (t < 32) {
            float re = 0.f, im = 0.f;
            #pragma unroll
            for (int q = 0; q < 8; ++q) { re += red[q][t].x; im += red[q][t].y; }
            const int state = ((t >> 4) << 5) | (nj << 4) | (t & 15);
            pri[(size_t)blockIdx.x * 64 + state] = make_float2(re, im);
        }
        __syncthreads();   // before next pass overwrites zuv/red
    }

    // part 3: combine per-wave stats -> per-block partials (verbatim R3/R4)
    if (t < 64) {
        const int wcn = t >> 5, nloc = t & 31;            // state n == t
        float M = stat_m[wcn][nloc], S = stat_s[wcn][nloc];
        onl(M, S, stat_m[wcn + 2][nloc], stat_s[wcn + 2][nloc]);
        pmphi[(size_t)blockIdx.x * 64 + t] = M;
        psphi[(size_t)blockIdx.x * 64 + t] = S;
    } else if (t < 128) {
        const int i = t - 64;
        float a = psr[i], bb = psr[i + 64];
        float M = fmaxf(a, bb);
        float S = fexp2((a - M) * LOG2E) + fexp2((bb - M) * LOG2E);
        #pragma unroll
        for (int off = 1; off <= 32; off <<= 1) {
            float m2 = __shfl_xor(M, off);
            float s2 = __shfl_xor(S, off);
            onl(M, S, m2, s2);
        }
        if (i == 0) { pmpsi[blockIdx.x] = M; pspsi[blockIdx.x] = S; }
    }
}

// K5: per batch: combine 32 block partials -> scales -> collapse -> out GEMM
__global__ __launch_bounds__(512) void k5_out(
        const float2* __restrict__ pri,
        const float* __restrict__ pmphi, const float* __restrict__ psphi,
        const float* __restrict__ pmpsi, const float* __restrict__ pspsi,
        const float* __restrict__ Smat, const float* __restrict__ sb_p,
        float* __restrict__ out) {
    const int b = blockIdx.x, t = threadIdx.x;
    __shared__ float cls[64];
    __shared__ float spsi_s;
    float sph = 0.f, re = 0.f, im = 0.f;
    if (t < 64) {
        float M = -3.4e38f, S = 0.f;
        for (int ch = 0; ch < 32; ++ch)
            onl(M, S, pmphi[(size_t)(b * 32 + ch) * 64 + t], psphi[(size_t)(b * 32 + ch) * 64 + t]);
        sph = fexp2(-M * HLOG2E) / sqrtf(S);              // exp(-M/2)/sqrt(sum exp(z-M)) = 1/sqrt(sum exp(z))
        for (int ch = 0; ch < 32; ++ch) {
            float2 p = pri[(size_t)(b * 32 + ch) * 64 + t];
            re += p.x; im += p.y;
        }
    } else if (t == 64) {
        float M = -3.4e38f, S = 0.f;
        for (int ch = 0; ch < 32; ++ch)
            onl(M, S, pmpsi[b * 32 + ch], pspsi[b * 32 + ch]);
        spsi_s = fexp2(-M * HLOG2E) / sqrtf(S);
    }
    __syncthreads();
    if (t < 64) {
        float sc = spsi_s * sph;
        cls[t] = sc * sc * (re * re + im * im);
    }
    __syncthreads();
    float acc = sb_p[0];
    #pragma unroll 8
    for (int n = 0; n < 64; ++n) acc = fmaf(cls[n], Smat[n * UNITS + t], acc);
    out[(size_t)b * UNITS + t] = acc;
}

extern "C" void kernel_launch(void* const* d_in, const int* in_sizes, int n_in,
                              void* d_out, int out_size, void* d_ws, size_t ws_size,
                              hipStream_t stream) {
    const float* x      = (const float*)d_in[0];
    const float* psi_r  = (const float*)d_in[1];
    const float* psi_t  = (const float*)d_in[2];
    const float* psi_tb = (const float*)d_in[3];
    const float* phi_r  = (const float*)d_in[4];
    const float* phi_t  = (const float*)d_in[5];
    const float* phi_tb = (const float*)d_in[6];
    const float* Smat   = (const float*)d_in[7];
    const float* sb     = (const float*)d_in[8];
    float* out = (float*)d_out;

    char* ws = (char*)d_ws;
    ushort* wht  = (ushort*)(ws + OFF_WHT);
    ushort* wlt  = (ushort*)(ws + OFF_WLT);
    float2* psw  = (float2*)(ws + OFF_PSW);
    float2* pri  = (float2*)(ws + OFF_PRI);
    float* pmphi = (float*)(ws + OFF_PMPHI);
    float* psphi = (float*)(ws + OFF_PSPHI);
    float* pmpsi = (float*)(ws + OFF_PMPSI);
    float* pspsi = (float*)(ws + OFF_PSPSI);

    k0_pack<<<512, 64, 0, stream>>>(psi_r, psi_t, phi_r, phi_t, wht, wlt, psw);
    k1_gemm<<<ROWS / 128, 256, 0, stream>>>(x, (const uint*)wht, (const uint*)wlt, psw,
                                            psi_tb, phi_tb, pri, pmphi, psphi, pmpsi, pspsi);
    k5_out<<<B_, 512, 0, stream>>>(pri, pmphi, psphi, pmpsi, pspsi, Smat, sb, out);
}